// Round 7
// baseline (117.328 us; speedup 1.0000x reference)
//
#include <hip/hip_runtime.h>
#include <hip/hip_bf16.h>

typedef _Float16 half8 __attribute__((ext_vector_type(8)));
typedef _Float16 h2    __attribute__((ext_vector_type(2)));
typedef float  float4v __attribute__((ext_vector_type(4)));

#define MFMAH __builtin_amdgcn_mfma_f32_16x16x32_f16
#define W2S 4160

union U8 { half8 v; h2 p[4]; int i[4]; };

// round-to-nearest-even f32 pair -> packed f16 (v_cvt_f16_f32 + v_pack_b32_f16)
__device__ __forceinline__ h2 pk_rne(float a, float b){
  h2 o; o[0] = (_Float16)a; o[1] = (_Float16)b; return o;
}
__device__ __forceinline__ float bf2f(unsigned short u){
  union { unsigned int i; float f; } x; x.i = ((unsigned int)u) << 16; return x.f;
}
__device__ __forceinline__ unsigned short f2bf(float f){
  union { float f; unsigned int i; } x; x.f = f;
  unsigned int r = x.i + 0x7FFFu + ((x.i >> 16) & 1u);
  return (unsigned short)(r >> 16);
}
__device__ __forceinline__ float ldin(const void* p, int i, bool isbf){
  return isbf ? bf2f(((const unsigned short*)p)[i]) : ((const float*)p)[i];
}
__device__ __forceinline__ float frcp(float x){ return __builtin_amdgcn_rcpf(x); }

// ws layout (bytes):
//   0       : gAF f16[4096*64]
//   524288  : gLF f16[4096*64]
//   1048576 : W2T f16[128][4160]  (k<4096 -> Km*u ; 4096..4159 -> e)

// register-resident halfstep: out = V * rcp(M @ x + 1); state stays in B0/B1
// (kappa-permuted A-frags make C-output packs == next B-operand, no LDS).
__device__ __forceinline__ void hstep_plain(const half8 (&A)[4][2], const float4v (&V)[4],
                                            half8& B0, half8& B1)
{
  const float4v ones = {1.f,1.f,1.f,1.f};
  float4v c[4];
  #pragma unroll
  for (int T = 0; T < 4; ++T) c[T] = MFMAH(A[T][0], B0, ones, 0, 0, 0);
  #pragma unroll
  for (int T = 0; T < 4; ++T) c[T] = MFMAH(A[T][1], B1, c[T], 0, 0, 0);
  U8 n0, n1;
  #pragma unroll
  for (int T = 0; T < 4; ++T){
    float o0 = V[T][0] * frcp(c[T][0]);
    float o1 = V[T][1] * frcp(c[T][1]);
    float o2 = V[T][2] * frcp(c[T][2]);
    float o3 = V[T][3] * frcp(c[T][3]);
    h2 pa = pk_rne(o0, o1);
    h2 pb = pk_rne(o2, o3);
    if (T < 2){ n0.p[2*T] = pa; n0.p[2*T+1] = pb; }
    else      { n1.p[2*(T-2)] = pa; n1.p[2*(T-2)+1] = pb; }
  }
  B0 = n0.v; B1 = n1.v;
}

__device__ __forceinline__ float hstep_err(const half8 (&A)[4][2], const float4v (&V)[4],
                                           half8& B0, half8& B1, float4v (&old)[4])
{
  const float4v ones = {1.f,1.f,1.f,1.f};
  float4v c[4];
  #pragma unroll
  for (int T = 0; T < 4; ++T) c[T] = MFMAH(A[T][0], B0, ones, 0, 0, 0);
  #pragma unroll
  for (int T = 0; T < 4; ++T) c[T] = MFMAH(A[T][1], B1, c[T], 0, 0, 0);
  U8 n0, n1;
  float worst = -1.f;
  #pragma unroll
  for (int T = 0; T < 4; ++T){
    float4v o;
    #pragma unroll
    for (int r = 0; r < 4; ++r){
      o[r] = V[T][r] * frcp(c[T][r]);
      float thr = old[T][r] * 7e-4f + 1e-6f;       // per-chain tol
      worst = fmaxf(worst, fabsf(o[r] - old[T][r]) - thr);
    }
    old[T] = o;
    h2 pa = pk_rne(o[0], o[1]);
    h2 pb = pk_rne(o[2], o[3]);
    if (T < 2){ n0.p[2*T] = pa; n0.p[2*T+1] = pb; }
    else      { n1.p[2*(T-2)] = pa; n1.p[2*(T-2)+1] = pb; }
  }
  B0 = n0.v; B1 = n1.v;
  return worst;
}

// ---------------- fused prep + iteration ----------------
// grid 386 x 128: bid<256 iter (wave0=AF-chain, wave1=LF-chain, 16 rows);
// 256..383 W2T u-builders (2 tiles each); 384..385 e-builders.
__global__ __launch_bounds__(128, 1) void k_fused(
    const void* LT, const void* K, const void* AT, const void* u,
    const void* e, const int* msin,
    _Float16* gAF, _Float16* gLF, _Float16* W2T)
{
  __shared__ __attribute__((aligned(16))) float sKf[64 * 65];  // reused by builders
  const int tid = threadIdx.x, bid = blockIdx.x;

  int ok = 0;
  if (tid < 64){
    float v = bf2f(((const unsigned short*)AT)[tid]);
    ok = (v >= 0.f && v <= 1.0f) ? 1 : 0;
  }
  int cnt = __syncthreads_count(ok);
  const bool isbf = (cnt >= 60);

  if (bid >= 256){
    if (bid < 384){
      float* sT = sKf;                      // 64 x 33
      const int ub = bid - 256;
      const int kl = tid & 63;
      for (int t2 = 0; t2 < 2; ++t2){
        const int t = ub * 2 + t2;
        const int k0 = (t >> 2) * 64, y0 = (t & 3) * 32, l = t >> 2;
        __syncthreads();
        #pragma unroll
        for (int i = 0; i < 16; ++i){
          int flat = i * 128 + tid, r = flat >> 5, c = flat & 31;
          sT[r * 33 + c] = ldin(u, (k0 + r) * 128 + y0 + c, isbf);
        }
        __syncthreads();
        float kmv = ldin(K, l * 64 + kl, isbf); kmv = fmaxf(kmv, 0.f);
        #pragma unroll
        for (int i = 0; i < 16; ++i){
          int yl = 2 * i + (tid >> 6);
          W2T[(y0 + yl) * W2S + k0 + kl] = (_Float16)(kmv * sT[kl * 33 + yl]);
        }
      }
    } else {
      float* sE = sKf;                      // 64 x 65
      const int y0 = (bid - 384) * 64;
      const int kl = tid & 63;
      #pragma unroll
      for (int i = 0; i < 32; ++i){
        int flat = i * 128 + tid, a = flat >> 6, c = flat & 63;
        sE[a * 65 + c] = ldin(e, a * 128 + y0 + c, isbf);
      }
      __syncthreads();
      #pragma unroll
      for (int i = 0; i < 32; ++i){
        int yl = 2 * i + (tid >> 6);
        W2T[(y0 + yl) * W2S + 4096 + kl] = (_Float16)sE[kl * 65 + yl];
      }
    }
    return;
  }

  // ---- iteration block ----
  #pragma unroll
  for (int i = 0; i < 32; ++i){
    int idx = i * 128 + tid, l = idx >> 6, a = idx & 63;
    sKf[l * 65 + a] = fmaxf(ldin(K, idx, isbf), 0.f);
  }
  __syncthreads();

  const int w = tid >> 6, lane = tid & 63;
  const int lr = lane & 15, q = lane >> 4;
  const int row0 = bid * 16;

  // kappa-permuted A-frags: element j multiplies state phys dim
  // kcol = 32ks + 16(j>>2) + 4q + (j&3); row m = 16T + lr.
  half8 a1[4][2], a2[4][2];
  #pragma unroll
  for (int T = 0; T < 4; ++T)
    #pragma unroll
    for (int ks = 0; ks < 2; ++ks){
      half8 f1, f2;
      #pragma unroll
      for (int j = 0; j < 8; ++j){
        int kcol = ks * 32 + ((j >> 2) * 16) + q * 4 + (j & 3);
        int row  = 16 * T + lr;
        float vKm = sKf[row * 65 + kcol];
        float vKT = sKf[kcol * 65 + row];
        f1[j] = (_Float16)(w ? vKT : vKm);
        f2[j] = (_Float16)(w ? vKm : vKT);
      }
      a1[T][ks] = f1; a2[T][ks] = f2;
    }

  float4v ltv[4], atv[4];
  if (isbf){
    const unsigned short* lt = (const unsigned short*)LT + (row0 + lr) * 64;
    const unsigned short* at = (const unsigned short*)AT;
    #pragma unroll
    for (int T = 0; T < 4; ++T)
      #pragma unroll
      for (int r = 0; r < 4; ++r){
        int d = 16 * T + q * 4 + r;
        ltv[T][r] = bf2f(lt[d]);
        atv[T][r] = fmaxf(bf2f(at[d]), 0.f);
      }
  } else {
    const float* lt = (const float*)LT + (row0 + lr) * 64;
    const float* at = (const float*)AT;
    #pragma unroll
    for (int T = 0; T < 4; ++T){
      ltv[T] = *(const float4v*)(lt + 16 * T + q * 4);
      float4v a = *(const float4v*)(at + 16 * T + q * 4);
      #pragma unroll
      for (int r = 0; r < 4; ++r) atv[T][r] = fmaxf(a[r], 0.f);
    }
  }
  float4v V1[4], V2[4];
  #pragma unroll
  for (int T = 0; T < 4; ++T){
    V1[T] = w ? atv[T] : ltv[T];
    V2[T] = w ? ltv[T] : atv[T];
  }

  int mi = msin[0];
  if (mi < 0 || mi > 1000000){
    float mf = ((const float*)msin)[0];
    mi = (mf >= 0.f && mf < 1.0e6f) ? (int)mf : 50;
  }

  half8 B0 = {}, B1 = {};
  float4v old[4] = {};

  // warm-up: no convergence logic (exit can't fire before ~step 9)
  int s = 0;
  const int warm = mi < 8 ? mi : 8;
  for (; s < warm; ++s){
    hstep_plain(a1, V1, B0, B1);
    hstep_plain(a2, V2, B0, B1);
  }
  int conv = 0;
  for (; s < mi && !conv; ++s){
    hstep_plain(a1, V1, B0, B1);
    float worst = hstep_err(a2, V2, B0, B1, old);
    conv = (__ballot(worst > 0.f) == 0ULL) ? 1 : 0;
  }
  // reference's post-loop extra step_fn
  hstep_plain(a1, V1, B0, B1);
  hstep_plain(a2, V2, B0, B1);

  // write final state (natural [row][dim] order, fp16)
  _Float16* gX = (w ? gLF : gAF) + (row0 + lr) * 64;
  int* g32 = (int*)gX;
  U8 ub0, ub1; ub0.v = B0; ub1.v = B1;
  #pragma unroll
  for (int T = 0; T < 4; ++T){
    int base = 8 * T + 2 * q;
    const U8& sx = (T < 2) ? ub0 : ub1;
    g32[base]     = sx.i[2 * (T & 1)];
    g32[base + 1] = sx.i[2 * (T & 1) + 1];
  }
}

// ---------------- epilogue ----------------
// grid 256 x 256: block = 32 rows x 64 y; wave = 16 rows x 32 y.
__global__ __launch_bounds__(256) void k_epi(
    const _Float16* gAF, const _Float16* gLF, const _Float16* W2T,
    const void* bvec, void* out)
{
  __shared__ __attribute__((aligned(16))) _Float16 sAF[32 * 72], sLF[32 * 72];
  const int tid = threadIdx.x, wv = tid >> 6, lane = tid & 63;
  const int lr = lane & 15, q = lane >> 4;

  int ok = 0;
  if (tid < 64){
    float v = bf2f(((const unsigned short*)bvec)[tid]);
    ok = (v >= 0.f && v <= 1.0f) ? 1 : 0;
  }
  int cnt = __syncthreads_count(ok);
  const bool isbf = (cnt >= 60);

  const int rows0 = (blockIdx.x >> 1) * 32, yh = blockIdx.x & 1;
  {
    int lrow = tid >> 3, seg = tid & 7;
    *(half8*)(sAF + lrow * 72 + seg * 8) =
        *(const half8*)(gAF + (rows0 + lrow) * 64 + seg * 8);
    *(half8*)(sLF + lrow * 72 + seg * 8) =
        *(const half8*)(gLF + (rows0 + lrow) * 64 + seg * 8);
  }
  __syncthreads();

  const int r0 = (wv & 1) * 16;
  const int y0 = yh * 64 + (wv >> 1) * 32;
  const int rloc = r0 + lr;

  const float bv0 = ldin(bvec, y0 + lr, isbf);
  const float bv1 = ldin(bvec, y0 + 16 + lr, isbf);
  float4v acc0 = {bv0, bv0, bv0, bv0};
  float4v acc1 = {bv1, bv1, bv1, bv1};

  U8 uaf0, uaf1;
  uaf0.v = *(const half8*)(sAF + rloc * 72 + q * 8);
  uaf1.v = *(const half8*)(sAF + rloc * 72 + 32 + q * 8);

  const _Float16* w0 = W2T + (y0 + lr) * W2S + q * 8;
  const _Float16* w1 = w0 + 16 * W2S;

  #pragma unroll 4
  for (int l = 0; l < 64; ++l){
    _Float16 lfv = sLF[rloc * 72 + l];
    h2 lf2 = {lfv, lfv};
    U8 d0, d1;
    #pragma unroll
    for (int i = 0; i < 4; ++i){
      d0.p[i] = lf2 * uaf0.p[i];            // v_pk_mul_f16
      d1.p[i] = lf2 * uaf1.p[i];
    }
    const int kb = l * 64;
    half8 b00 = *(const half8*)(w0 + kb);
    half8 b01 = *(const half8*)(w0 + kb + 32);
    half8 b10 = *(const half8*)(w1 + kb);
    half8 b11 = *(const half8*)(w1 + kb + 32);
    acc0 = MFMAH(d0.v, b00, acc0, 0, 0, 0);
    acc0 = MFMAH(d1.v, b01, acc0, 0, 0, 0);
    acc1 = MFMAH(d0.v, b10, acc1, 0, 0, 0);
    acc1 = MFMAH(d1.v, b11, acc1, 0, 0, 0);
  }
  {  // e-term: k = 4096..4159, A-operand = AF raw
    half8 b00 = *(const half8*)(w0 + 4096);
    half8 b01 = *(const half8*)(w0 + 4096 + 32);
    half8 b10 = *(const half8*)(w1 + 4096);
    half8 b11 = *(const half8*)(w1 + 4096 + 32);
    acc0 = MFMAH(uaf0.v, b00, acc0, 0, 0, 0);
    acc0 = MFMAH(uaf1.v, b01, acc0, 0, 0, 0);
    acc1 = MFMAH(uaf0.v, b10, acc1, 0, 0, 0);
    acc1 = MFMAH(uaf1.v, b11, acc1, 0, 0, 0);
  }

  if (isbf){
    unsigned short* o = (unsigned short*)out;
    #pragma unroll
    for (int r = 0; r < 4; ++r){
      int orow = rows0 + r0 + q * 4 + r;
      o[orow * 128 + y0 + lr]      = f2bf(acc0[r]);
      o[orow * 128 + y0 + 16 + lr] = f2bf(acc1[r]);
    }
  } else {
    float* o = (float*)out;
    #pragma unroll
    for (int r = 0; r < 4; ++r){
      int orow = rows0 + r0 + q * 4 + r;
      o[orow * 128 + y0 + lr]      = acc0[r];
      o[orow * 128 + y0 + 16 + lr] = acc1[r];
    }
  }
}

extern "C" void kernel_launch(void* const* d_in, const int* in_sizes, int n_in,
                              void* d_out, int out_size, void* d_ws, size_t ws_size,
                              hipStream_t stream){
  char* ws = (char*)d_ws;
  _Float16* gAF = (_Float16*)(ws);
  _Float16* gLF = (_Float16*)(ws + 524288);
  _Float16* W2T = (_Float16*)(ws + 1048576);

  k_fused<<<dim3(386), dim3(128), 0, stream>>>(
      d_in[0], d_in[1], d_in[2], d_in[3], d_in[4], (const int*)d_in[6],
      gAF, gLF, W2T);
  k_epi<<<dim3(256), dim3(256), 0, stream>>>(
      gAF, gLF, W2T, d_in[5], d_out);
}